// Round 5
// baseline (360.979 us; speedup 1.0000x reference)
//
#include <hip/hip_runtime.h>
#include <hip/hip_bf16.h>

#define N_NODES 10000
#define N_EDGES 160000

typedef __hip_bfloat16 bf16;
typedef unsigned short u16;
typedef float f32x4 __attribute__((ext_vector_type(4)));
typedef short s16x8 __attribute__((ext_vector_type(8)));
typedef unsigned short us8 __attribute__((ext_vector_type(8)));
typedef unsigned short us4 __attribute__((ext_vector_type(4)));

static __device__ __forceinline__ float b2f(u16 u) {
    unsigned v = (unsigned)u << 16;
    return __uint_as_float(v);
}
static __device__ __forceinline__ u16 f2b(float f) {
    bf16 b = __float2bfloat16(f);
    return *reinterpret_cast<u16*>(&b);
}

// ---------------- prep: x conv + edge extract + degree count + W transposes ------
// blocks [0,2500): xb convert (4 f32->bf16 per thread) + edge extract + deg count.
// blocks [2500, 2500+1024): transpose WT[n][k] = bf16(W[k][n]).
// deg must be zeroed before (hipMemsetAsync).

__global__ void k_prep(const int* __restrict__ ei, const float* __restrict__ x,
                       u16* __restrict__ xb,
                       int* __restrict__ row, int* __restrict__ col,
                       int* __restrict__ deg,
                       const float* __restrict__ W1, const float* __restrict__ W2,
                       const float* __restrict__ W3, const float* __restrict__ W4,
                       u16* __restrict__ T1, u16* __restrict__ T2,
                       u16* __restrict__ T3, u16* __restrict__ T4) {
    __shared__ u16 tile[32][33];
    if (blockIdx.x < 2500) {
        int t = blockIdx.x * 256 + threadIdx.x;  // 0 .. 639999
        float4 v = *(const float4*)(x + (size_t)t * 4);
        us4 st;
        st[0] = f2b(v.x); st[1] = f2b(v.y); st[2] = f2b(v.z); st[3] = f2b(v.w);
        *(us4*)(xb + (size_t)t * 4) = st;

        if (t < N_EDGES) {
            bool is64 = true;
#pragma unroll
            for (int k = 0; k < 8; ++k) is64 = is64 && (ei[2 * k + 1] == 0);
            int r, c;
            if (is64) {
                r = ei[2 * t];
                c = ei[2 * (N_EDGES + t)];
            } else {
                r = ei[t];
                c = ei[N_EDGES + t];
            }
            row[t] = r;
            col[t] = c;
            atomicAdd(&deg[c], 1);
        }
        return;
    }
    int b = blockIdx.x - 2500;        // 0..1023
    int z = b >> 8;                   // 0..3
    int rem = b & 255;
    int by = rem >> 4, bx = rem & 15;
    const float* W = (z == 0) ? W1 : (z == 1) ? W2 : (z == 2) ? W3 : W4;
    u16* WT        = (z == 0) ? T1 : (z == 1) ? T2 : (z == 2) ? T3 : T4;
    int K = (z == 0) ? 256 : 512;
    int k0 = by * 32;
    if (k0 >= K) return;
    int n0 = bx * 32;
    int tx = threadIdx.x & 31, ty = threadIdx.x >> 5;  // 32 x 8
    for (int i = 0; i < 32; i += 8)
        tile[ty + i][tx] = f2b(W[(size_t)(k0 + ty + i) * 512 + n0 + tx]);
    __syncthreads();
    for (int i = 0; i < 32; i += 8)
        WT[(size_t)(n0 + ty + i) * K + k0 + tx] = tile[tx][ty + i];
}

// Single block: dis = rsqrt(deg+1); exclusive scan of deg -> off, cur.
__global__ void k_scan_all(const int* __restrict__ deg, float* __restrict__ dis,
                           int* __restrict__ off, int* __restrict__ cur) {
    __shared__ int sd[N_NODES];   // 40 KB
    __shared__ int sums[256];
    int t = threadIdx.x;
    for (int i = t; i < N_NODES; i += 256) {
        int d = deg[i];
        sd[i] = d;
        dis[i] = rsqrtf((float)d + 1.0f);
    }
    __syncthreads();
    const int seg = (N_NODES + 255) >> 8;  // 40
    int lo = t * seg, hi = lo + seg;
    if (lo > N_NODES) lo = N_NODES;
    if (hi > N_NODES) hi = N_NODES;
    int s = 0;
    for (int i = lo; i < hi; ++i) s += sd[i];
    sums[t] = s;
    __syncthreads();
    for (int d = 1; d < 256; d <<= 1) {
        int v = (t >= d) ? sums[t - d] : 0;
        __syncthreads();
        sums[t] += v;
        __syncthreads();
    }
    int run = sums[t] - s;
    for (int i = lo; i < hi; ++i) {
        off[i] = run;
        cur[i] = run;
        run += sd[i];
    }
    if (t == 255) off[N_NODES] = sums[255];
}

// ---------------- fill CSR (by dst) ----------------------------------------------

__global__ void k_fill(const int* __restrict__ row, const int* __restrict__ col,
                       const float* __restrict__ dis, int* cur,
                       int* __restrict__ crow, float* __restrict__ cnorm) {
    int e = blockIdx.x * 256 + threadIdx.x;
    if (e < N_EDGES) {
        int r = row[e], c = col[e];
        int p = atomicAdd(&cur[c], 1);
        crow[p] = r;
        cnorm[p] = dis[r] * dis[c];
    }
}

// ---------------- fused layer: Y = act(Agg(X) @ W + b) ----------------------------
// One block per 16 output rows (625 blocks exactly; 10000 = 625*16). 256 threads.
// Phase 1: wave w gathers rows {4w..4w+3}: f32 accumulate over CSR neighbors
//          (8-deep MLP, 4 chains), convert bf16, write 16xK A-tile to LDS with
//          XOR swizzle (full_byte_offset ^ ((row&7)<<4)) -> 2-way reads (free).
// Phase 2: one barrier; barrier-free MFMA loop. A frags from LDS; B frags
//          streamed from WT (512KB, L2-resident in every XCD) directly into regs.
// Wave w computes cols [w*128, w*128+128): acc[8] of 16x16 frags.
// NOTE swizzle rule (#21): XOR must be applied to the COMPLETE byte offset on
// both sides. R4 bug: read did (base^s)+kb*64 -> bit-6 carry corrupted rows 4-7,
// 12-15 on odd kb. Fixed: (base+kb*64)^s.

template <int CE> struct VecT;
template <> struct VecT<4> { typedef us4 T; };
template <> struct VecT<8> { typedef us8 T; };

static __device__ __forceinline__ void st_out(float* out, size_t idx, float v) { out[idx] = v; }
static __device__ __forceinline__ void st_out(u16* out, size_t idx, float v) { out[idx] = f2b(v); }

template <int K, typename OT>
__global__ __launch_bounds__(256, 3) void k_layer(
        const u16* __restrict__ X, const u16* __restrict__ WT,
        const float* __restrict__ bias, OT* __restrict__ Y,
        const int* __restrict__ off, const int* __restrict__ crow,
        const float* __restrict__ cnorm, const float* __restrict__ dis,
        int relu) {
    constexpr int CE = K / 64;            // channels per lane: 4 or 8
    typedef typename VecT<CE>::T VT;
    __shared__ u16 As[16 * K];            // swizzled [16][K] bf16 (8/16 KB)

    int tid = threadIdx.x;
    int w = tid >> 6;
    int lane = tid & 63;
    int m0 = blockIdx.x * 16;

    // ---------- phase 1: gather 4 rows per wave ----------
    const u16* inp = X + lane * CE;
    for (int rr = 0; rr < 4; ++rr) {
        int rowl = w * 4 + rr;            // 0..15
        int node = m0 + rowl;             // exact, no clamp (10000 = 625*16)
        float dn = dis[node];
        VT sv = *(const VT*)(inp + (size_t)node * K);
        float a0[CE], a1[CE], a2[CE], a3[CE];
#pragma unroll
        for (int j = 0; j < CE; ++j) {
            a0[j] = b2f(sv[j]) * dn * dn;
            a1[j] = 0.f; a2[j] = 0.f; a3[j] = 0.f;
        }
        int lo = off[node], hi = off[node + 1];
        int i = lo;
        for (; i + 7 < hi; i += 8) {
            int r[8]; float nn[8]; VT v[8];
#pragma unroll
            for (int q = 0; q < 8; ++q) { r[q] = crow[i + q]; nn[q] = cnorm[i + q]; }
#pragma unroll
            for (int q = 0; q < 8; ++q) v[q] = *(const VT*)(inp + (size_t)r[q] * K);
#pragma unroll
            for (int j = 0; j < CE; ++j) {
                a0[j] = fmaf(b2f(v[0][j]), nn[0], a0[j]);
                a1[j] = fmaf(b2f(v[1][j]), nn[1], a1[j]);
                a2[j] = fmaf(b2f(v[2][j]), nn[2], a2[j]);
                a3[j] = fmaf(b2f(v[3][j]), nn[3], a3[j]);
            }
#pragma unroll
            for (int j = 0; j < CE; ++j) {
                a0[j] = fmaf(b2f(v[4][j]), nn[4], a0[j]);
                a1[j] = fmaf(b2f(v[5][j]), nn[5], a1[j]);
                a2[j] = fmaf(b2f(v[6][j]), nn[6], a2[j]);
                a3[j] = fmaf(b2f(v[7][j]), nn[7], a3[j]);
            }
        }
        for (; i + 3 < hi; i += 4) {
            int r0 = crow[i], r1 = crow[i + 1], r2 = crow[i + 2], r3 = crow[i + 3];
            float n0 = cnorm[i], n1 = cnorm[i + 1], n2 = cnorm[i + 2], n3 = cnorm[i + 3];
            VT v0 = *(const VT*)(inp + (size_t)r0 * K);
            VT v1 = *(const VT*)(inp + (size_t)r1 * K);
            VT v2 = *(const VT*)(inp + (size_t)r2 * K);
            VT v3 = *(const VT*)(inp + (size_t)r3 * K);
#pragma unroll
            for (int j = 0; j < CE; ++j) {
                a0[j] = fmaf(b2f(v0[j]), n0, a0[j]);
                a1[j] = fmaf(b2f(v1[j]), n1, a1[j]);
                a2[j] = fmaf(b2f(v2[j]), n2, a2[j]);
                a3[j] = fmaf(b2f(v3[j]), n3, a3[j]);
            }
        }
        for (; i < hi; ++i) {
            int r0 = crow[i];
            float n0 = cnorm[i];
            VT v0 = *(const VT*)(inp + (size_t)r0 * K);
#pragma unroll
            for (int j = 0; j < CE; ++j) a0[j] = fmaf(b2f(v0[j]), n0, a0[j]);
        }
        VT st;
#pragma unroll
        for (int j = 0; j < CE; ++j) st[j] = f2b((a0[j] + a1[j]) + (a2[j] + a3[j]));
        unsigned byteoff = (unsigned)(rowl * K + lane * CE) * 2u;
        byteoff ^= (unsigned)((rowl & 7) << 4);            // full-offset XOR (G4/#21)
        *(VT*)((char*)As + byteoff) = st;
    }
    __syncthreads();

    // ---------- phase 2: MFMA, A from LDS, B from L2 ----------
    int l15 = lane & 15;
    int kq = lane >> 4;  // 0..3
    f32x4 acc[8];
#pragma unroll
    for (int ni = 0; ni < 8; ++ni) acc[ni] = (f32x4){0.f, 0.f, 0.f, 0.f};

    const u16* bbase = WT + (size_t)(w * 128 + l15) * K + kq * 8;
    unsigned abase0 = (unsigned)(l15 * K + kq * 8) * 2u;   // un-swizzled base
    unsigned swz = (unsigned)((l15 & 7) << 4);

#pragma unroll 4
    for (int kb = 0; kb < K / 32; ++kb) {
        // full offset assembled FIRST, then XOR (matches write side)
        s16x8 a = *(const s16x8*)((const char*)As + ((abase0 + (unsigned)kb * 64u) ^ swz));
        s16x8 bb[8];
#pragma unroll
        for (int ni = 0; ni < 8; ++ni)
            bb[ni] = *(const s16x8*)(bbase + (size_t)ni * 16 * K + kb * 32);
#pragma unroll
        for (int ni = 0; ni < 8; ++ni)
            acc[ni] = __builtin_amdgcn_mfma_f32_16x16x32_bf16(a, bb[ni], acc[ni], 0, 0, 0);
    }

    // C/D layout: col = lane&15, row = (lane>>4)*4 + r   [m89-verified]
    int cn = w * 128;
    float bv[8];
#pragma unroll
    for (int ni = 0; ni < 8; ++ni) bv[ni] = bias[cn + ni * 16 + l15];
#pragma unroll
    for (int r = 0; r < 4; ++r) {
        int node = m0 + kq * 4 + r;
#pragma unroll
        for (int ni = 0; ni < 8; ++ni) {
            float v = acc[ni][r] + bv[ni];
            if (relu) v = fmaxf(v, 0.f);
            st_out(Y, (size_t)node * 512 + cn + ni * 16 + l15, v);
        }
    }
}

// ---------------- launch ----------------

extern "C" void kernel_launch(void* const* d_in, const int* in_sizes, int n_in,
                              void* d_out, int out_size, void* d_ws, size_t ws_size,
                              hipStream_t stream) {
    const float* x  = (const float*)d_in[0];
    const int*   ei = (const int*)d_in[1];
    const float* W1 = (const float*)d_in[2];
    const float* b1 = (const float*)d_in[3];
    const float* W2 = (const float*)d_in[4];
    const float* b2 = (const float*)d_in[5];
    const float* W3 = (const float*)d_in[6];
    const float* b3 = (const float*)d_in[7];
    const float* W4 = (const float*)d_in[8];
    const float* b4 = (const float*)d_in[9];

    char* ws = (char*)d_ws;
    size_t o = 0;
    auto alloc = [&](size_t bytes) {
        char* p = ws + o;
        o = (o + bytes + 255) & ~(size_t)255;
        return p;
    };
    int*   row   = (int*)alloc(N_EDGES * 4);
    int*   col   = (int*)alloc(N_EDGES * 4);
    int*   deg   = (int*)alloc(N_NODES * 4);
    float* dis   = (float*)alloc(N_NODES * 4);
    int*   off   = (int*)alloc((N_NODES + 1) * 4);
    int*   cur   = (int*)alloc(N_NODES * 4);
    int*   crow  = (int*)alloc(N_EDGES * 4);
    float* cnorm = (float*)alloc(N_EDGES * 4);
    u16*   WT1   = (u16*)alloc((size_t)512 * 256 * 2);
    u16*   WT2   = (u16*)alloc((size_t)512 * 512 * 2);
    u16*   WT3   = (u16*)alloc((size_t)512 * 512 * 2);
    u16*   WT4   = (u16*)alloc((size_t)512 * 512 * 2);
    u16*   xb    = (u16*)alloc((size_t)N_NODES * 256 * 2);  // bf16 x
    u16*   h     = (u16*)alloc((size_t)N_NODES * 512 * 2);  // bf16 hidden A
    u16*   g     = (u16*)alloc((size_t)N_NODES * 512 * 2);  // bf16 hidden B
    float* outb  = (float*)d_out;

    dim3 b256(256);

    hipMemsetAsync(deg, 0, N_NODES * 4, stream);
    k_prep<<<2500 + 1024, b256, 0, stream>>>(ei, x, xb, row, col, deg,
                                             W1, W2, W3, W4, WT1, WT2, WT3, WT4);
    k_scan_all<<<1, b256, 0, stream>>>(deg, dis, off, cur);
    k_fill<<<625, b256, 0, stream>>>(row, col, dis, cur, crow, cnorm);

    k_layer<256, u16 ><<<625, b256, 0, stream>>>(xb, WT1, b1, h, off, crow, cnorm, dis, 1);
    k_layer<512, u16 ><<<625, b256, 0, stream>>>(h,  WT2, b2, g, off, crow, cnorm, dis, 1);
    k_layer<512, u16 ><<<625, b256, 0, stream>>>(g,  WT3, b3, h, off, crow, cnorm, dis, 1);
    k_layer<512, float><<<625, b256, 0, stream>>>(h, WT4, b4, outb, off, crow, cnorm, dis, 0);
}